// Round 1
// baseline (598.816 us; speedup 1.0000x reference)
//
#include <hip/hip_runtime.h>
#include <cstdint>
#include <cstddef>

// ---------------------------------------------------------------------------
// CausalSelfAttention: y = proj(softmax_causal(QK^T/sqrt(HD)) V), QKV = x@W_attn+b
// B=2 T=2048 C=2048 H=16 HD=128. All I/O fp32; internal compute bf16 MFMA.
// ---------------------------------------------------------------------------

typedef __bf16 bf16x8 __attribute__((ext_vector_type(8)));
typedef float  f32x4  __attribute__((ext_vector_type(4)));

__device__ __forceinline__ unsigned short f2bf(float f) {
  unsigned int u = __builtin_bit_cast(unsigned int, f);
  u += 0x7fffu + ((u >> 16) & 1u);       // round-to-nearest-even
  return (unsigned short)(u >> 16);
}

__device__ __forceinline__ void gld16(void* lds, const void* g) {
  // async global->LDS, 16B per lane; LDS dest is wave-uniform base + lane*16
  __builtin_amdgcn_global_load_lds(
      (const __attribute__((address_space(1))) void*)g,
      (__attribute__((address_space(3))) void*)lds, 16, 0, 0);
}

// ---------------------------------------------------------------------------
// fp32 -> bf16 elementwise (x conversion)
// ---------------------------------------------------------------------------
__global__ void cvt_f32_bf16_k(const float* __restrict__ in,
                               unsigned short* __restrict__ out, int n4) {
  int i = blockIdx.x * blockDim.x + threadIdx.x;
  int stride = gridDim.x * blockDim.x;
  for (; i < n4; i += stride) {
    float4 v = ((const float4*)in)[i];
    ushort4 o;
    o.x = f2bf(v.x); o.y = f2bf(v.y); o.z = f2bf(v.z); o.w = f2bf(v.w);
    ((ushort4*)out)[i] = o;
  }
}

// ---------------------------------------------------------------------------
// fp32 (R,C) -> bf16 transposed (C,R)   [for W_attn / W_proj -> B^T layout]
// ---------------------------------------------------------------------------
__global__ void transpose_f32_bf16(const float* __restrict__ in,
                                   unsigned short* __restrict__ out,
                                   int R, int C) {
  __shared__ float tile[32][33];
  int c0 = blockIdx.x * 32, r0 = blockIdx.y * 32;
  int tx = threadIdx.x, ty = threadIdx.y;
#pragma unroll
  for (int i = 0; i < 4; i++)
    tile[ty + i * 8][tx] = in[(size_t)(r0 + ty + i * 8) * C + c0 + tx];
  __syncthreads();
#pragma unroll
  for (int i = 0; i < 4; i++)
    out[(size_t)(c0 + ty + i * 8) * R + r0 + tx] = f2bf(tile[tx][ty + i * 8]);
}

// ---------------------------------------------------------------------------
// extract V^T (B,H,HD,T) bf16 from qkv (B*T, 3C) bf16
// ---------------------------------------------------------------------------
__global__ void extract_vT_k(const unsigned short* __restrict__ qkv,
                             unsigned short* __restrict__ vT) {
  __shared__ unsigned short tile[32][33];
  int bh = blockIdx.z;            // b*16+h
  int b = bh >> 4, h = bh & 15;
  int t0 = blockIdx.x * 32, d0 = blockIdx.y * 32;
  int tx = threadIdx.x, ty = threadIdx.y;
  const unsigned short* src = qkv + (size_t)(b * 2048) * 6144 + 4096 + h * 128;
#pragma unroll
  for (int i = 0; i < 4; i++)
    tile[ty + i * 8][tx] = src[(size_t)(t0 + ty + i * 8) * 6144 + d0 + tx];
  __syncthreads();
  unsigned short* dst = vT + (size_t)bh * 128 * 2048;
#pragma unroll
  for (int i = 0; i < 4; i++)
    dst[(size_t)(d0 + ty + i * 8) * 2048 + t0 + tx] = tile[tx][ty + i * 8];
}

// ---------------------------------------------------------------------------
// m97-style GEMM: C[M,N] = A[M,K](bf16) * BT[N,K](bf16)^T + bias
// 128x128 tile, BK=32, 4 waves (2x2 of 64x64), global_load_lds width-16.
// OUT_BF16=1 -> bf16 out, else fp32 out.
// ---------------------------------------------------------------------------
template <int OUT_BF16>
__global__ __launch_bounds__(256) void gemm_bt(
    const unsigned short* __restrict__ A, const unsigned short* __restrict__ BT,
    const float* __restrict__ bias, void* __restrict__ Cout,
    int M, int N, int K) {
  __shared__ __align__(16) unsigned short sA[128 * 32];
  __shared__ __align__(16) unsigned short sB[128 * 32];

  const int tid = threadIdx.x, w = tid >> 6, lane = tid & 63;
  const int quad = lane >> 4, l16 = lane & 15;
  const int m0 = blockIdx.y * 128, n0 = blockIdx.x * 128;
  const int wr = w >> 1, wc = w & 1;

  // staging: 512 chunks of 16B per tile; wave w owns chunks [w*128, w*128+128)
  const int c0 = w * 128 + lane;        // i=0 chunk
  const int c1 = w * 128 + 64 + lane;   // i=1 chunk
  const unsigned short* gA0 = A + (size_t)(m0 + (c0 >> 2)) * K + (c0 & 3) * 8;
  const unsigned short* gA1 = A + (size_t)(m0 + (c1 >> 2)) * K + (c1 & 3) * 8;
  const unsigned short* gB0 = BT + (size_t)(n0 + (c0 >> 2)) * K + (c0 & 3) * 8;
  const unsigned short* gB1 = BT + (size_t)(n0 + (c1 >> 2)) * K + (c1 & 3) * 8;
  unsigned short* lA0 = sA + (size_t)(w * 128) * 8;
  unsigned short* lA1 = sA + (size_t)(w * 128 + 64) * 8;
  unsigned short* lB0 = sB + (size_t)(w * 128) * 8;
  unsigned short* lB1 = sB + (size_t)(w * 128 + 64) * 8;

  f32x4 acc[4][4] = {};

  for (int k0 = 0; k0 < K; k0 += 32) {
    gld16(lA0, gA0); gld16(lA1, gA1);
    gld16(lB0, gB0); gld16(lB1, gB1);
    gA0 += 32; gA1 += 32; gB0 += 32; gB1 += 32;
    __syncthreads();

    bf16x8 af[4], bfr[4];
#pragma unroll
    for (int mi = 0; mi < 4; mi++)
      af[mi] = *(const bf16x8*)&sA[(wr * 64 + mi * 16 + l16) * 32 + quad * 8];
#pragma unroll
    for (int ni = 0; ni < 4; ni++)
      bfr[ni] = *(const bf16x8*)&sB[(wc * 64 + ni * 16 + l16) * 32 + quad * 8];
#pragma unroll
    for (int mi = 0; mi < 4; mi++)
#pragma unroll
      for (int ni = 0; ni < 4; ni++)
        acc[mi][ni] = __builtin_amdgcn_mfma_f32_16x16x32_bf16(
            af[mi], bfr[ni], acc[mi][ni], 0, 0, 0);
    __syncthreads();
  }

  // epilogue: C/D layout row = quad*4+reg, col = l16
#pragma unroll
  for (int mi = 0; mi < 4; mi++) {
    int row = m0 + wr * 64 + mi * 16 + quad * 4;
#pragma unroll
    for (int ni = 0; ni < 4; ni++) {
      int col = n0 + wc * 64 + ni * 16 + l16;
      float bv = bias[col];
#pragma unroll
      for (int r = 0; r < 4; r++) {
        float v = acc[mi][ni][r] + bv;
        if (OUT_BF16)
          ((unsigned short*)Cout)[(size_t)(row + r) * N + col] = f2bf(v);
        else
          ((float*)Cout)[(size_t)(row + r) * N + col] = v;
      }
    }
  }
}

// ---------------------------------------------------------------------------
// Flash attention (causal). One block = 64 Q rows for one (b,h).
// 4 waves x 16 Q rows. K-tiles of 64. Q frags in registers; K,V^T staged to
// LDS via global_load_lds; P round-trips through per-wave LDS (m120 pattern).
// ---------------------------------------------------------------------------
__global__ __launch_bounds__(256) void flash_attn(
    const unsigned short* __restrict__ qkv, const unsigned short* __restrict__ vT,
    unsigned short* __restrict__ yout) {
  __shared__ __align__(16) unsigned short sK[64 * 128];    // [t_k][d]
  __shared__ __align__(16) unsigned short sVT[128 * 64];   // [d][t_k]
  __shared__ __align__(16) unsigned short sP[4 * 16 * 64]; // per-wave 16x64

  const int tid = threadIdx.x, w = tid >> 6, lane = tid & 63;
  const int quad = lane >> 4, l16 = lane & 15;
  const int qt = blockIdx.x, h = blockIdx.y, b = blockIdx.z;
  const int q0 = qt * 64;
  const int T = 2048, CC = 6144, HD = 128;
  const float rscale = 0.08838834764831845f;  // 1/sqrt(128)

  // Q fragments: A-layout A[m=l16][k=quad*8+j]; row t = q0 + w*16 + l16
  const size_t qrow = (size_t)(b * T + q0 + w * 16 + l16) * CC + h * HD;
  bf16x8 qf[4];
#pragma unroll
  for (int kb = 0; kb < 4; kb++)
    qf[kb] = *(const bf16x8*)&qkv[qrow + kb * 32 + quad * 8];

  float m_old[4], l_sum[4];
  f32x4 o[8] = {};
#pragma unroll
  for (int r = 0; r < 4; r++) { m_old[r] = -1e30f; l_sum[r] = 0.f; }

  const unsigned short* gK = qkv + (size_t)(b * T) * CC + 2048 + h * HD;
  const unsigned short* gV = vT + (size_t)(b * 16 + h) * HD * T;
  unsigned short* pw = sP + w * 16 * 64;

  for (int kt = 0; kt <= qt; ++kt) {
    // stage K tile (64x128) and V^T tile (128x64), 1024 chunks each
#pragma unroll
    for (int i = 0; i < 4; i++) {
      int c = w * 256 + i * 64 + lane;
      gld16(sK + (size_t)(w * 256 + i * 64) * 8,
            gK + (size_t)(kt * 64 + (c >> 4)) * CC + (c & 15) * 8);
      gld16(sVT + (size_t)(w * 256 + i * 64) * 8,
            gV + (size_t)(c >> 3) * T + kt * 64 + (c & 7) * 8);
    }
    __syncthreads();

    // S = Q K^T : 16x64 per wave
    f32x4 s[4] = {};
#pragma unroll
    for (int kb = 0; kb < 4; kb++) {
#pragma unroll
      for (int cb = 0; cb < 4; cb++) {
        bf16x8 kf = *(const bf16x8*)&sK[(cb * 16 + l16) * 128 + kb * 32 + quad * 8];
        s[cb] = __builtin_amdgcn_mfma_f32_16x16x32_bf16(qf[kb], kf, s[cb], 0, 0, 0);
      }
    }

    // scale + causal mask
    float sv[4][4];
#pragma unroll
    for (int cb = 0; cb < 4; cb++)
#pragma unroll
      for (int r = 0; r < 4; r++) {
        float v = s[cb][r] * rscale;
        if (kt == qt) {
          int col = kt * 64 + cb * 16 + l16;
          int row = q0 + w * 16 + quad * 4 + r;
          if (col > row) v = -1e30f;
        }
        sv[cb][r] = v;
      }

    // online softmax per row (row lives in 16 lanes of one quad)
    float alpha[4];
#pragma unroll
    for (int r = 0; r < 4; r++) {
      float mx = fmaxf(fmaxf(sv[0][r], sv[1][r]), fmaxf(sv[2][r], sv[3][r]));
#pragma unroll
      for (int off = 8; off >= 1; off >>= 1) mx = fmaxf(mx, __shfl_xor(mx, off, 16));
      float m_new = fmaxf(m_old[r], mx);
      float a = __expf(m_old[r] - m_new);
      float ssum = 0.f;
#pragma unroll
      for (int cb = 0; cb < 4; cb++) {
        float p = __expf(sv[cb][r] - m_new);
        sv[cb][r] = p;
        ssum += p;
      }
#pragma unroll
      for (int off = 8; off >= 1; off >>= 1) ssum += __shfl_xor(ssum, off, 16);
      l_sum[r] = l_sum[r] * a + ssum;
      m_old[r] = m_new;
      alpha[r] = a;
    }

    // rescale O
#pragma unroll
    for (int nb = 0; nb < 8; nb++)
#pragma unroll
      for (int r = 0; r < 4; r++) o[nb][r] *= alpha[r];

    // P (C/D layout) -> per-wave LDS, row-major 16x64
#pragma unroll
    for (int cb = 0; cb < 4; cb++)
#pragma unroll
      for (int r = 0; r < 4; r++)
        pw[(quad * 4 + r) * 64 + cb * 16 + l16] = f2bf(sv[cb][r]);

    // O += P V : P A-frag from LDS, V^T B-frag from LDS
#pragma unroll
    for (int kb2 = 0; kb2 < 2; kb2++) {
      bf16x8 pf = *(const bf16x8*)&pw[l16 * 64 + kb2 * 32 + quad * 8];
#pragma unroll
      for (int nb = 0; nb < 8; nb++) {
        bf16x8 vf = *(const bf16x8*)&sVT[(nb * 16 + l16) * 64 + kb2 * 32 + quad * 8];
        o[nb] = __builtin_amdgcn_mfma_f32_16x16x32_bf16(pf, vf, o[nb], 0, 0, 0);
      }
    }
    __syncthreads();
  }

  // epilogue: y[(b*T+t)*C + h*HD + d] bf16
#pragma unroll
  for (int r = 0; r < 4; r++) {
    float inv = 1.0f / l_sum[r];
    size_t orow = (size_t)(b * T + q0 + w * 16 + quad * 4 + r) * 2048 + h * HD;
#pragma unroll
    for (int nb = 0; nb < 8; nb++)
      yout[orow + nb * 16 + l16] = f2bf(o[nb][r] * inv);
  }
}

// ---------------------------------------------------------------------------
extern "C" void kernel_launch(void* const* d_in, const int* in_sizes, int n_in,
                              void* d_out, int out_size, void* d_ws, size_t ws_size,
                              hipStream_t stream) {
  const float* x      = (const float*)d_in[0];   // (2,2048,2048)
  const float* W_attn = (const float*)d_in[1];   // (2048,6144)
  const float* b_attn = (const float*)d_in[2];   // (6144,)
  const float* W_proj = (const float*)d_in[3];   // (2048,2048)
  const float* b_proj = (const float*)d_in[4];   // (2048,)
  float* out = (float*)d_out;                    // (2,2048,2048) fp32

  char* ws = (char*)d_ws;
  unsigned short* x_bf  = (unsigned short*)(ws);              // 16 MiB
  unsigned short* WaT   = (unsigned short*)(ws + 16777216);   // 24 MiB
  unsigned short* WpT   = (unsigned short*)(ws + 41943040);   // 8 MiB
  unsigned short* qkv   = (unsigned short*)(ws + 50331648);   // 48 MiB
  unsigned short* vT    = (unsigned short*)(ws + 100663296);  // 16 MiB
  unsigned short* y_att = (unsigned short*)(ws + 117440512);  // 16 MiB
  // total 128 MiB

  cvt_f32_bf16_k<<<1024, 256, 0, stream>>>(x, x_bf, 8388608 / 4);
  transpose_f32_bf16<<<dim3(192, 64), dim3(32, 8), 0, stream>>>(W_attn, WaT, 2048, 6144);
  transpose_f32_bf16<<<dim3(64, 64), dim3(32, 8), 0, stream>>>(W_proj, WpT, 2048, 2048);
  gemm_bt<1><<<dim3(48, 32), 256, 0, stream>>>(x_bf, WaT, b_attn, qkv, 4096, 6144, 2048);
  extract_vT_k<<<dim3(64, 4, 32), dim3(32, 8), 0, stream>>>(qkv, vT);
  flash_attn<<<dim3(32, 16, 2), 256, 0, stream>>>(qkv, vT, y_att);
  gemm_bt<0><<<dim3(16, 32), 256, 0, stream>>>(y_att, WpT, b_proj, out, 4096, 2048, 2048);
}

// Round 2
// 517.086 us; speedup vs baseline: 1.1581x; 1.1581x over previous
//
#include <hip/hip_runtime.h>
#include <cstdint>
#include <cstddef>

// ---------------------------------------------------------------------------
// CausalSelfAttention: y = proj(softmax_causal(QK^T/sqrt(HD)) V), QKV = x@W_attn+b
// B=2 T=2048 C=2048 H=16 HD=128. All I/O fp32; internal compute bf16 MFMA.
// ---------------------------------------------------------------------------

typedef __bf16 bf16x8 __attribute__((ext_vector_type(8)));
typedef float  f32x4  __attribute__((ext_vector_type(4)));

__device__ __forceinline__ unsigned short f2bf(float f) {
  unsigned int u = __builtin_bit_cast(unsigned int, f);
  u += 0x7fffu + ((u >> 16) & 1u);       // round-to-nearest-even
  return (unsigned short)(u >> 16);
}

__device__ __forceinline__ void gld16(void* lds, const void* g) {
  // async global->LDS, 16B per lane; LDS dest is wave-uniform base + lane*16
  __builtin_amdgcn_global_load_lds(
      (const __attribute__((address_space(1))) void*)g,
      (__attribute__((address_space(3))) void*)lds, 16, 0, 0);
}

// ---------------------------------------------------------------------------
// fp32 -> bf16 elementwise (x conversion)
// ---------------------------------------------------------------------------
__global__ void cvt_f32_bf16_k(const float* __restrict__ in,
                               unsigned short* __restrict__ out, int n4) {
  int i = blockIdx.x * blockDim.x + threadIdx.x;
  int stride = gridDim.x * blockDim.x;
  for (; i < n4; i += stride) {
    float4 v = ((const float4*)in)[i];
    ushort4 o;
    o.x = f2bf(v.x); o.y = f2bf(v.y); o.z = f2bf(v.z); o.w = f2bf(v.w);
    ((ushort4*)out)[i] = o;
  }
}

// ---------------------------------------------------------------------------
// fp32 (R,C) -> bf16 transposed (C,R)   [for W_attn / W_proj -> B^T layout]
// ---------------------------------------------------------------------------
__global__ void transpose_f32_bf16(const float* __restrict__ in,
                                   unsigned short* __restrict__ out,
                                   int R, int C) {
  __shared__ float tile[32][33];
  int c0 = blockIdx.x * 32, r0 = blockIdx.y * 32;
  int tx = threadIdx.x, ty = threadIdx.y;
#pragma unroll
  for (int i = 0; i < 4; i++)
    tile[ty + i * 8][tx] = in[(size_t)(r0 + ty + i * 8) * C + c0 + tx];
  __syncthreads();
#pragma unroll
  for (int i = 0; i < 4; i++)
    out[(size_t)(c0 + ty + i * 8) * R + r0 + tx] = f2bf(tile[tx][ty + i * 8]);
}

// ---------------------------------------------------------------------------
// extract V^T (B,H,HD,T) bf16 from qkv (B*T, 3C) bf16
// ---------------------------------------------------------------------------
__global__ void extract_vT_k(const unsigned short* __restrict__ qkv,
                             unsigned short* __restrict__ vT) {
  __shared__ unsigned short tile[32][33];
  int bh = blockIdx.z;            // b*16+h
  int b = bh >> 4, h = bh & 15;
  int t0 = blockIdx.x * 32, d0 = blockIdx.y * 32;
  int tx = threadIdx.x, ty = threadIdx.y;
  const unsigned short* src = qkv + (size_t)(b * 2048) * 6144 + 4096 + h * 128;
#pragma unroll
  for (int i = 0; i < 4; i++)
    tile[ty + i * 8][tx] = src[(size_t)(t0 + ty + i * 8) * 6144 + d0 + tx];
  __syncthreads();
  unsigned short* dst = vT + (size_t)bh * 128 * 2048;
#pragma unroll
  for (int i = 0; i < 4; i++)
    dst[(size_t)(d0 + ty + i * 8) * 2048 + t0 + tx] = tile[tx][ty + i * 8];
}

// ---------------------------------------------------------------------------
// m97-style GEMM: C[M,N] = A[M,K](bf16) * BT[N,K](bf16)^T + bias
// 128x128 tile, BK=32, 4 waves (2x2 of 64x64), global_load_lds width-16.
// OUT_BF16=1 -> bf16 out, else fp32 out.
// ---------------------------------------------------------------------------
template <int OUT_BF16>
__global__ __launch_bounds__(256) void gemm_bt(
    const unsigned short* __restrict__ A, const unsigned short* __restrict__ BT,
    const float* __restrict__ bias, void* __restrict__ Cout,
    int M, int N, int K) {
  __shared__ __align__(16) unsigned short sA[128 * 32];
  __shared__ __align__(16) unsigned short sB[128 * 32];

  const int tid = threadIdx.x, w = tid >> 6, lane = tid & 63;
  const int quad = lane >> 4, l16 = lane & 15;
  const int m0 = blockIdx.y * 128, n0 = blockIdx.x * 128;
  const int wr = w >> 1, wc = w & 1;

  // staging: 512 chunks of 16B per tile; wave w owns chunks [w*128, w*128+128)
  const int c0 = w * 128 + lane;        // i=0 chunk
  const int c1 = w * 128 + 64 + lane;   // i=1 chunk
  const unsigned short* gA0 = A + (size_t)(m0 + (c0 >> 2)) * K + (c0 & 3) * 8;
  const unsigned short* gA1 = A + (size_t)(m0 + (c1 >> 2)) * K + (c1 & 3) * 8;
  const unsigned short* gB0 = BT + (size_t)(n0 + (c0 >> 2)) * K + (c0 & 3) * 8;
  const unsigned short* gB1 = BT + (size_t)(n0 + (c1 >> 2)) * K + (c1 & 3) * 8;
  unsigned short* lA0 = sA + (size_t)(w * 128) * 8;
  unsigned short* lA1 = sA + (size_t)(w * 128 + 64) * 8;
  unsigned short* lB0 = sB + (size_t)(w * 128) * 8;
  unsigned short* lB1 = sB + (size_t)(w * 128 + 64) * 8;

  f32x4 acc[4][4] = {};

  for (int k0 = 0; k0 < K; k0 += 32) {
    gld16(lA0, gA0); gld16(lA1, gA1);
    gld16(lB0, gB0); gld16(lB1, gB1);
    gA0 += 32; gA1 += 32; gB0 += 32; gB1 += 32;
    __syncthreads();

    bf16x8 af[4], bfr[4];
#pragma unroll
    for (int mi = 0; mi < 4; mi++)
      af[mi] = *(const bf16x8*)&sA[(wr * 64 + mi * 16 + l16) * 32 + quad * 8];
#pragma unroll
    for (int ni = 0; ni < 4; ni++)
      bfr[ni] = *(const bf16x8*)&sB[(wc * 64 + ni * 16 + l16) * 32 + quad * 8];
#pragma unroll
    for (int mi = 0; mi < 4; mi++)
#pragma unroll
      for (int ni = 0; ni < 4; ni++)
        acc[mi][ni] = __builtin_amdgcn_mfma_f32_16x16x32_bf16(
            af[mi], bfr[ni], acc[mi][ni], 0, 0, 0);
    __syncthreads();
  }

  // epilogue: C/D layout row = quad*4+reg, col = l16
#pragma unroll
  for (int mi = 0; mi < 4; mi++) {
    int row = m0 + wr * 64 + mi * 16 + quad * 4;
#pragma unroll
    for (int ni = 0; ni < 4; ni++) {
      int col = n0 + wc * 64 + ni * 16 + l16;
      float bv = bias[col];
#pragma unroll
      for (int r = 0; r < 4; r++) {
        float v = acc[mi][ni][r] + bv;
        if (OUT_BF16)
          ((unsigned short*)Cout)[(size_t)(row + r) * N + col] = f2bf(v);
        else
          ((float*)Cout)[(size_t)(row + r) * N + col] = v;
      }
    }
  }
}

// ---------------------------------------------------------------------------
// Flash attention (causal). One block = TWO complementary 64-row Q tiles
// (qp and 31-qp) for one (b,h) -> every block does exactly 33 k-tile
// iterations (load balance). 4 waves x 16 Q rows per tile.
// LDS layouts XOR-swizzled so ds_read_b128 is bank-conflict-free while
// keeping global_load_lds's lane-contiguous destination requirement:
//   LDS slot (row, chunk) holds global chunk (row, chunk ^ (row & mask)).
// ---------------------------------------------------------------------------
__global__ __launch_bounds__(256) void flash_attn(
    const unsigned short* __restrict__ qkv, const unsigned short* __restrict__ vT,
    unsigned short* __restrict__ yout) {
  __shared__ __align__(16) unsigned short sK[64 * 128];    // [t_k][d], 16 chunks/row, swizzle &15
  __shared__ __align__(16) unsigned short sVT[128 * 64];   // [d][t_k],  8 chunks/row, swizzle &7
  __shared__ __align__(16) unsigned short sP[4 * 16 * 64]; // per-wave 16x64, 8 chunks/row, swizzle &7

  const int tid = threadIdx.x, w = tid >> 6, lane = tid & 63;
  const int quad = lane >> 4, l16 = lane & 15;
  const int qp = blockIdx.x, h = blockIdx.y, b = blockIdx.z;
  const int T = 2048, CC = 6144, HD = 128;
  const float rscale = 0.08838834764831845f;  // 1/sqrt(128)

  const unsigned short* gK = qkv + (size_t)(b * T) * CC + 2048 + h * HD;
  const unsigned short* gV = vT + (size_t)(b * 16 + h) * HD * T;
  unsigned short* pw = sP + w * 16 * 64;

  // precompute swizzled staging source offsets (slot -> global chunk)
  int kRow[4], kCol[4], vRow[4], vCol[4];
#pragma unroll
  for (int i = 0; i < 4; i++) {
    int c = w * 256 + i * 64 + lane;
    kRow[i] = c >> 4;
    kCol[i] = (c & 15) ^ (kRow[i] & 15);
    vRow[i] = c >> 3;
    vCol[i] = (c & 7) ^ (vRow[i] & 7);
  }

#pragma unroll
  for (int half = 0; half < 2; half++) {
    const int qt = half ? (31 - qp) : qp;
    const int q0 = qt * 64;

    // Q fragments: A-layout A[m=l16][k=quad*8+j]; row t = q0 + w*16 + l16
    const size_t qrow = (size_t)(b * T + q0 + w * 16 + l16) * CC + h * HD;
    bf16x8 qf[4];
#pragma unroll
    for (int kb = 0; kb < 4; kb++)
      qf[kb] = *(const bf16x8*)&qkv[qrow + kb * 32 + quad * 8];

    float m_old[4], l_sum[4];
    f32x4 o[8] = {};
#pragma unroll
    for (int r = 0; r < 4; r++) { m_old[r] = -1e30f; l_sum[r] = 0.f; }

    for (int kt = 0; kt <= qt; ++kt) {
      // stage K tile (64x128) and V^T tile (128x64), swizzled chunk sources
#pragma unroll
      for (int i = 0; i < 4; i++) {
        gld16(sK + (size_t)(w * 256 + i * 64) * 8,
              gK + (size_t)(kt * 64 + kRow[i]) * CC + kCol[i] * 8);
        gld16(sVT + (size_t)(w * 256 + i * 64) * 8,
              gV + (size_t)vRow[i] * T + kt * 64 + vCol[i] * 8);
      }
      __syncthreads();

      // S = Q K^T : 16x64 per wave.  B-frag row rr=cb*16+l16, chunk cc=kb*4+quad
      f32x4 s[4] = {};
#pragma unroll
      for (int kb = 0; kb < 4; kb++) {
#pragma unroll
        for (int cb = 0; cb < 4; cb++) {
          int rr = cb * 16 + l16;
          int cc = (kb * 4 + quad) ^ l16;      // rr & 15 == l16
          bf16x8 kf = *(const bf16x8*)&sK[rr * 128 + cc * 8];
          s[cb] = __builtin_amdgcn_mfma_f32_16x16x32_bf16(qf[kb], kf, s[cb], 0, 0, 0);
        }
      }

      // scale + causal mask
      float sv[4][4];
#pragma unroll
      for (int cb = 0; cb < 4; cb++)
#pragma unroll
        for (int r = 0; r < 4; r++) {
          float v = s[cb][r] * rscale;
          if (kt == qt) {
            int col = kt * 64 + cb * 16 + l16;
            int row = q0 + w * 16 + quad * 4 + r;
            if (col > row) v = -1e30f;
          }
          sv[cb][r] = v;
        }

      // online softmax per row (row lives in 16 lanes of one quad)
      float alpha[4];
#pragma unroll
      for (int r = 0; r < 4; r++) {
        float mx = fmaxf(fmaxf(sv[0][r], sv[1][r]), fmaxf(sv[2][r], sv[3][r]));
#pragma unroll
        for (int off = 8; off >= 1; off >>= 1) mx = fmaxf(mx, __shfl_xor(mx, off, 16));
        float m_new = fmaxf(m_old[r], mx);
        float a = __expf(m_old[r] - m_new);
        float ssum = 0.f;
#pragma unroll
        for (int cb = 0; cb < 4; cb++) {
          float p = __expf(sv[cb][r] - m_new);
          sv[cb][r] = p;
          ssum += p;
        }
#pragma unroll
        for (int off = 8; off >= 1; off >>= 1) ssum += __shfl_xor(ssum, off, 16);
        l_sum[r] = l_sum[r] * a + ssum;
        m_old[r] = m_new;
        alpha[r] = a;
      }

      // rescale O
#pragma unroll
      for (int nb = 0; nb < 8; nb++)
#pragma unroll
        for (int r = 0; r < 4; r++) o[nb][r] *= alpha[r];

      // P (C/D layout) -> per-wave LDS, swizzled row-major 16x64
#pragma unroll
      for (int cb = 0; cb < 4; cb++) {
#pragma unroll
        for (int r = 0; r < 4; r++) {
          int prow = quad * 4 + r;
          int pcol = cb * 16 + l16;
          int pcc = (pcol >> 3) ^ (prow & 7);
          pw[prow * 64 + pcc * 8 + (pcol & 7)] = f2bf(sv[cb][r]);
        }
      }

      // O += P V : P A-frag row rr=l16, chunk cc=kb2*4+quad (swizzled)
#pragma unroll
      for (int kb2 = 0; kb2 < 2; kb2++) {
        int pcc = (kb2 * 4 + quad) ^ (l16 & 7);
        bf16x8 pf = *(const bf16x8*)&pw[l16 * 64 + pcc * 8];
#pragma unroll
        for (int nb = 0; nb < 8; nb++) {
          int rr = nb * 16 + l16;
          int cc = (kb2 * 4 + quad) ^ (rr & 7);
          bf16x8 vf = *(const bf16x8*)&sVT[rr * 64 + cc * 8];
          o[nb] = __builtin_amdgcn_mfma_f32_16x16x32_bf16(pf, vf, o[nb], 0, 0, 0);
        }
      }
      __syncthreads();
    }

    // epilogue: y[(b*T+t)*C + h*HD + d] bf16
#pragma unroll
    for (int r = 0; r < 4; r++) {
      float inv = 1.0f / l_sum[r];
      size_t orow = (size_t)(b * T + q0 + w * 16 + quad * 4 + r) * 2048 + h * HD;
#pragma unroll
      for (int nb = 0; nb < 8; nb++)
        yout[orow + nb * 16 + l16] = f2bf(o[nb][r] * inv);
    }
  }
}

// ---------------------------------------------------------------------------
extern "C" void kernel_launch(void* const* d_in, const int* in_sizes, int n_in,
                              void* d_out, int out_size, void* d_ws, size_t ws_size,
                              hipStream_t stream) {
  const float* x      = (const float*)d_in[0];   // (2,2048,2048)
  const float* W_attn = (const float*)d_in[1];   // (2048,6144)
  const float* b_attn = (const float*)d_in[2];   // (6144,)
  const float* W_proj = (const float*)d_in[3];   // (2048,2048)
  const float* b_proj = (const float*)d_in[4];   // (2048,)
  float* out = (float*)d_out;                    // (2,2048,2048) fp32

  char* ws = (char*)d_ws;
  unsigned short* x_bf  = (unsigned short*)(ws);              // 16 MiB
  unsigned short* WaT   = (unsigned short*)(ws + 16777216);   // 24 MiB
  unsigned short* WpT   = (unsigned short*)(ws + 41943040);   // 8 MiB
  unsigned short* qkv   = (unsigned short*)(ws + 50331648);   // 48 MiB
  unsigned short* vT    = (unsigned short*)(ws + 100663296);  // 16 MiB
  unsigned short* y_att = (unsigned short*)(ws + 117440512);  // 16 MiB
  // total 128 MiB

  cvt_f32_bf16_k<<<1024, 256, 0, stream>>>(x, x_bf, 8388608 / 4);
  transpose_f32_bf16<<<dim3(192, 64), dim3(32, 8), 0, stream>>>(W_attn, WaT, 2048, 6144);
  transpose_f32_bf16<<<dim3(64, 64), dim3(32, 8), 0, stream>>>(W_proj, WpT, 2048, 2048);
  gemm_bt<1><<<dim3(48, 32), 256, 0, stream>>>(x_bf, WaT, b_attn, qkv, 4096, 6144, 2048);
  extract_vT_k<<<dim3(64, 4, 32), dim3(32, 8), 0, stream>>>(qkv, vT);
  flash_attn<<<dim3(16, 16, 2), 256, 0, stream>>>(qkv, vT, y_att);
  gemm_bt<0><<<dim3(16, 32), 256, 0, stream>>>(y_att, WpT, b_proj, out, 4096, 2048, 2048);
}

// Round 3
// 440.298 us; speedup vs baseline: 1.3600x; 1.1744x over previous
//
#include <hip/hip_runtime.h>
#include <cstdint>
#include <cstddef>

// ---------------------------------------------------------------------------
// CausalSelfAttention: y = proj(softmax_causal(QK^T/sqrt(HD)) V), QKV = x@W_attn+b
// B=2 T=2048 C=2048 H=16 HD=128. All I/O fp32; internal compute bf16 MFMA.
// ---------------------------------------------------------------------------

typedef __bf16 bf16x8 __attribute__((ext_vector_type(8)));
typedef float  f32x4  __attribute__((ext_vector_type(4)));

__device__ __forceinline__ unsigned short f2bf(float f) {
  unsigned int u = __builtin_bit_cast(unsigned int, f);
  u += 0x7fffu + ((u >> 16) & 1u);       // round-to-nearest-even
  return (unsigned short)(u >> 16);
}

__device__ __forceinline__ void gld16(void* lds, const void* g) {
  // async global->LDS, 16B per lane; LDS dest is wave-uniform base + lane*16
  __builtin_amdgcn_global_load_lds(
      (const __attribute__((address_space(1))) void*)g,
      (__attribute__((address_space(3))) void*)lds, 16, 0, 0);
}

// ---------------------------------------------------------------------------
// fp32 -> bf16 elementwise (x conversion)
// ---------------------------------------------------------------------------
__global__ void cvt_f32_bf16_k(const float* __restrict__ in,
                               unsigned short* __restrict__ out, int n4) {
  int i = blockIdx.x * blockDim.x + threadIdx.x;
  int stride = gridDim.x * blockDim.x;
  for (; i < n4; i += stride) {
    float4 v = ((const float4*)in)[i];
    ushort4 o;
    o.x = f2bf(v.x); o.y = f2bf(v.y); o.z = f2bf(v.z); o.w = f2bf(v.w);
    ((ushort4*)out)[i] = o;
  }
}

// ---------------------------------------------------------------------------
// fp32 (R,C) -> bf16 transposed (C,R)   [for W_attn / W_proj -> B^T layout]
// ---------------------------------------------------------------------------
__global__ void transpose_f32_bf16(const float* __restrict__ in,
                                   unsigned short* __restrict__ out,
                                   int R, int C) {
  __shared__ float tile[32][33];
  int c0 = blockIdx.x * 32, r0 = blockIdx.y * 32;
  int tx = threadIdx.x, ty = threadIdx.y;
#pragma unroll
  for (int i = 0; i < 4; i++)
    tile[ty + i * 8][tx] = in[(size_t)(r0 + ty + i * 8) * C + c0 + tx];
  __syncthreads();
#pragma unroll
  for (int i = 0; i < 4; i++)
    out[(size_t)(c0 + ty + i * 8) * R + r0 + tx] = f2bf(tile[tx][ty + i * 8]);
}

// ---------------------------------------------------------------------------
// extract V^T (B,H,HD,T) bf16 from qkv (B*T, 3C) bf16
// ---------------------------------------------------------------------------
__global__ void extract_vT_k(const unsigned short* __restrict__ qkv,
                             unsigned short* __restrict__ vT) {
  __shared__ unsigned short tile[32][33];
  int bh = blockIdx.z;            // b*16+h
  int b = bh >> 4, h = bh & 15;
  int t0 = blockIdx.x * 32, d0 = blockIdx.y * 32;
  int tx = threadIdx.x, ty = threadIdx.y;
  const unsigned short* src = qkv + (size_t)(b * 2048) * 6144 + 4096 + h * 128;
#pragma unroll
  for (int i = 0; i < 4; i++)
    tile[ty + i * 8][tx] = src[(size_t)(t0 + ty + i * 8) * 6144 + d0 + tx];
  __syncthreads();
  unsigned short* dst = vT + (size_t)bh * 128 * 2048;
#pragma unroll
  for (int i = 0; i < 4; i++)
    dst[(size_t)(d0 + ty + i * 8) * 2048 + t0 + tx] = tile[tx][ty + i * 8];
}

// ---------------------------------------------------------------------------
// m97-style GEMM: C[M,N] = A[M,K](bf16) * BT[N,K](bf16)^T + bias
// 128x128 tile, BK=32, 4 waves (2x2 of 64x64), global_load_lds width-16.
// OUT_BF16=1 -> bf16 out, else fp32 out.
// ---------------------------------------------------------------------------
template <int OUT_BF16>
__global__ __launch_bounds__(256) void gemm_bt(
    const unsigned short* __restrict__ A, const unsigned short* __restrict__ BT,
    const float* __restrict__ bias, void* __restrict__ Cout,
    int M, int N, int K) {
  __shared__ __align__(16) unsigned short sA[128 * 32];
  __shared__ __align__(16) unsigned short sB[128 * 32];

  const int tid = threadIdx.x, w = tid >> 6, lane = tid & 63;
  const int quad = lane >> 4, l16 = lane & 15;
  const int m0 = blockIdx.y * 128, n0 = blockIdx.x * 128;
  const int wr = w >> 1, wc = w & 1;

  // staging: 512 chunks of 16B per tile; wave w owns chunks [w*128, w*128+128)
  const int c0 = w * 128 + lane;        // i=0 chunk
  const int c1 = w * 128 + 64 + lane;   // i=1 chunk
  const unsigned short* gA0 = A + (size_t)(m0 + (c0 >> 2)) * K + (c0 & 3) * 8;
  const unsigned short* gA1 = A + (size_t)(m0 + (c1 >> 2)) * K + (c1 & 3) * 8;
  const unsigned short* gB0 = BT + (size_t)(n0 + (c0 >> 2)) * K + (c0 & 3) * 8;
  const unsigned short* gB1 = BT + (size_t)(n0 + (c1 >> 2)) * K + (c1 & 3) * 8;
  unsigned short* lA0 = sA + (size_t)(w * 128) * 8;
  unsigned short* lA1 = sA + (size_t)(w * 128 + 64) * 8;
  unsigned short* lB0 = sB + (size_t)(w * 128) * 8;
  unsigned short* lB1 = sB + (size_t)(w * 128 + 64) * 8;

  f32x4 acc[4][4] = {};

  for (int k0 = 0; k0 < K; k0 += 32) {
    gld16(lA0, gA0); gld16(lA1, gA1);
    gld16(lB0, gB0); gld16(lB1, gB1);
    gA0 += 32; gA1 += 32; gB0 += 32; gB1 += 32;
    __syncthreads();

    bf16x8 af[4], bfr[4];
#pragma unroll
    for (int mi = 0; mi < 4; mi++)
      af[mi] = *(const bf16x8*)&sA[(wr * 64 + mi * 16 + l16) * 32 + quad * 8];
#pragma unroll
    for (int ni = 0; ni < 4; ni++)
      bfr[ni] = *(const bf16x8*)&sB[(wc * 64 + ni * 16 + l16) * 32 + quad * 8];
#pragma unroll
    for (int mi = 0; mi < 4; mi++)
#pragma unroll
      for (int ni = 0; ni < 4; ni++)
        acc[mi][ni] = __builtin_amdgcn_mfma_f32_16x16x32_bf16(
            af[mi], bfr[ni], acc[mi][ni], 0, 0, 0);
    __syncthreads();
  }

  // epilogue: C/D layout row = quad*4+reg, col = l16
#pragma unroll
  for (int mi = 0; mi < 4; mi++) {
    int row = m0 + wr * 64 + mi * 16 + quad * 4;
#pragma unroll
    for (int ni = 0; ni < 4; ni++) {
      int col = n0 + wc * 64 + ni * 16 + l16;
      float bv = bias[col];
#pragma unroll
      for (int r = 0; r < 4; r++) {
        float v = acc[mi][ni][r] + bv;
        if (OUT_BF16)
          ((unsigned short*)Cout)[(size_t)(row + r) * N + col] = f2bf(v);
        else
          ((float*)Cout)[(size_t)(row + r) * N + col] = v;
      }
    }
  }
}

// ---------------------------------------------------------------------------
// Flash attention (causal). Linear grid of 512:
//   g  = id & 31  -> (b,h) group; all 16 qp-blocks of g land on XCD g%8
//                    (round-robin dispatch heuristic -> K/V stays in one L2)
//   qp = id >> 5  -> complementary q-tile pair (qp, 31-qp): 33 k-iters/block
// Flattened 33-iteration loop over both segments with DOUBLE-BUFFERED K/V
// staging: prefetch tile it+1 right after the top barrier, compute tile it.
// LDS XOR-swizzled (slot (row,chunk) holds global chunk (row, chunk^row&mask))
// so ds_read_b128 is conflict-free under global_load_lds's lane-contiguous
// destination constraint. Q pre-scaled by (1/sqrt(HD))*log2e; exp2f softmax.
// ---------------------------------------------------------------------------
__global__ __launch_bounds__(256) void flash_attn(
    const unsigned short* __restrict__ qkv, const unsigned short* __restrict__ vT,
    unsigned short* __restrict__ yout) {
  __shared__ __align__(16) unsigned short sK[2][64 * 128];    // [t_k][d], swizzle &15
  __shared__ __align__(16) unsigned short sVT[2][128 * 64];   // [d][t_k], swizzle &7
  __shared__ __align__(16) unsigned short sP[4 * 16 * 64];    // per-wave 16x64, swizzle &7

  const int tid = threadIdx.x, w = tid >> 6, lane = tid & 63;
  const int quad = lane >> 4, l16 = lane & 15;
  const int id = blockIdx.x;
  const int g = id & 31;           // (b,h) group -> XCD g%8
  const int qp = id >> 5;          // 0..15
  const int b = g >> 4, h = g & 15;
  const int T = 2048, CC = 6144, HD = 128;
  const float qscale = 0.12753257252f;  // (1/sqrt(128)) * log2(e)

  const unsigned short* gK = qkv + (size_t)(b * T) * CC + 2048 + h * HD;
  const unsigned short* gV = vT + (size_t)(b * 16 + h) * HD * T;
  unsigned short* pw = sP + w * 16 * 64;

  // swizzled staging source pointers (slot -> global chunk), tile-invariant part
  const unsigned short* kSrc[4];
  const unsigned short* vSrc[4];
  unsigned short* kDst[4];
  unsigned short* vDst[4];
#pragma unroll
  for (int i = 0; i < 4; i++) {
    int c = w * 256 + i * 64 + lane;
    int kR = c >> 4, kC = (c & 15) ^ (kR & 15);
    int vR = c >> 3, vC = (c & 7) ^ (vR & 7);
    kSrc[i] = gK + (size_t)kR * CC + kC * 8;
    vSrc[i] = gV + (size_t)vR * T + vC * 8;
    kDst[i] = (unsigned short*)sK + (size_t)(w * 256 + i * 64) * 8;
    vDst[i] = (unsigned short*)sVT + (size_t)(w * 256 + i * 64) * 8;
  }
  const int KBUF = 64 * 128, VBUF = 128 * 64;

  const int qtA = qp, qtB = 31 - qp;
  int qt = qtA, kt = 0;

  // ---- per-segment state ----
  bf16x8 qf[4];
  float m_old[4], l_sum[4];
  f32x4 o[8] = {};
  {
    const size_t qrow = (size_t)(b * T + qt * 64 + w * 16 + l16) * CC + h * HD;
#pragma unroll
    for (int kb = 0; kb < 4; kb++) {
      bf16x8 raw = *(const bf16x8*)&qkv[qrow + kb * 32 + quad * 8];
      bf16x8 sc;
#pragma unroll
      for (int j = 0; j < 8; j++) sc[j] = (__bf16)((float)raw[j] * qscale);
      qf[kb] = sc;
    }
  }
#pragma unroll
  for (int r = 0; r < 4; r++) { m_old[r] = -1e30f; l_sum[r] = 0.f; }

  // stage tile 0 into buffer 0
#pragma unroll
  for (int i = 0; i < 4; i++) {
    gld16(kDst[i], kSrc[i]);
    gld16(vDst[i], vSrc[i]);
  }

  const int total = qtA + qtB + 2;   // = 33
  for (int it = 0; it < total; ++it) {
    __syncthreads();                 // buf[it&1] staged; prev iter's LDS reads done
    const int cur = it & 1;
    const bool segEnd = (kt == qt);

    // prefetch next tile into the other buffer (overlaps with compute below)
    if (it + 1 < total) {
      const int nkt = segEnd ? 0 : kt + 1;
      const int nb_ = (it + 1) & 1;
      const size_t kOff = (size_t)nkt * 64 * CC;   // K rows advance
      const int vOff = nkt * 64;                   // V cols advance
#pragma unroll
      for (int i = 0; i < 4; i++) {
        gld16(kDst[i] + (size_t)nb_ * KBUF * 8 / 8, kSrc[i] + kOff);
        gld16(vDst[i] + (size_t)nb_ * VBUF, vSrc[i] + vOff);
      }
    }

    // S = Q K^T : 16x64 per wave (log2-domain logits; Q pre-scaled)
    const unsigned short* sKc = (const unsigned short*)sK + (size_t)cur * KBUF;
    const unsigned short* sVc = (const unsigned short*)sVT + (size_t)cur * VBUF;
    f32x4 s4[4] = {};
#pragma unroll
    for (int kb = 0; kb < 4; kb++) {
#pragma unroll
      for (int cb = 0; cb < 4; cb++) {
        int rr = cb * 16 + l16;
        int cc = (kb * 4 + quad) ^ l16;
        bf16x8 kf = *(const bf16x8*)&sKc[rr * 128 + cc * 8];
        s4[cb] = __builtin_amdgcn_mfma_f32_16x16x32_bf16(qf[kb], kf, s4[cb], 0, 0, 0);
      }
    }

    // causal mask (diagonal tile only == segment end)
    float sv[4][4];
#pragma unroll
    for (int cb = 0; cb < 4; cb++)
#pragma unroll
      for (int r = 0; r < 4; r++) {
        float v = s4[cb][r];
        if (segEnd) {
          int col = cb * 16 + l16;
          int row = w * 16 + quad * 4 + r;
          if (col > row) v = -1e30f;
        }
        sv[cb][r] = v;
      }

    // online softmax per row (base-2 exponentials)
    float alpha[4];
#pragma unroll
    for (int r = 0; r < 4; r++) {
      float mx = fmaxf(fmaxf(sv[0][r], sv[1][r]), fmaxf(sv[2][r], sv[3][r]));
#pragma unroll
      for (int off = 8; off >= 1; off >>= 1) mx = fmaxf(mx, __shfl_xor(mx, off, 16));
      float m_new = fmaxf(m_old[r], mx);
      float a = exp2f(m_old[r] - m_new);
      float ssum = 0.f;
#pragma unroll
      for (int cb = 0; cb < 4; cb++) {
        float p = exp2f(sv[cb][r] - m_new);
        sv[cb][r] = p;
        ssum += p;
      }
#pragma unroll
      for (int off = 8; off >= 1; off >>= 1) ssum += __shfl_xor(ssum, off, 16);
      l_sum[r] = l_sum[r] * a + ssum;
      m_old[r] = m_new;
      alpha[r] = a;
    }

    // rescale O
#pragma unroll
    for (int nb = 0; nb < 8; nb++)
#pragma unroll
      for (int r = 0; r < 4; r++) o[nb][r] *= alpha[r];

    // P (C/D layout) -> per-wave LDS, swizzled row-major 16x64
#pragma unroll
    for (int cb = 0; cb < 4; cb++) {
#pragma unroll
      for (int r = 0; r < 4; r++) {
        int prow = quad * 4 + r;
        int pcol = cb * 16 + l16;
        int pcc = (pcol >> 3) ^ (prow & 7);
        pw[prow * 64 + pcc * 8 + (pcol & 7)] = f2bf(sv[cb][r]);
      }
    }

    // O += P V
#pragma unroll
    for (int kb2 = 0; kb2 < 2; kb2++) {
      int pcc = (kb2 * 4 + quad) ^ (l16 & 7);
      bf16x8 pf = *(const bf16x8*)&pw[l16 * 64 + pcc * 8];
#pragma unroll
      for (int nb = 0; nb < 8; nb++) {
        int rr = nb * 16 + l16;
        int cc = (kb2 * 4 + quad) ^ (rr & 7);
        bf16x8 vf = *(const bf16x8*)&sVc[rr * 64 + cc * 8];
        o[nb] = __builtin_amdgcn_mfma_f32_16x16x32_bf16(pf, vf, o[nb], 0, 0, 0);
      }
    }

    if (segEnd) {
      // segment epilogue: y[(b*T+t)*C + h*HD + d] bf16
#pragma unroll
      for (int r = 0; r < 4; r++) {
        float inv = 1.0f / l_sum[r];
        size_t orow = (size_t)(b * T + qt * 64 + w * 16 + quad * 4 + r) * 2048 + h * HD;
#pragma unroll
        for (int nb = 0; nb < 8; nb++)
          yout[orow + nb * 16 + l16] = f2bf(o[nb][r] * inv);
      }
      if (it + 1 < total) {
        // reset state for segment B
        qt = qtB;
        const size_t qrow = (size_t)(b * T + qt * 64 + w * 16 + l16) * CC + h * HD;
#pragma unroll
        for (int kb = 0; kb < 4; kb++) {
          bf16x8 raw = *(const bf16x8*)&qkv[qrow + kb * 32 + quad * 8];
          bf16x8 sc;
#pragma unroll
          for (int j = 0; j < 8; j++) sc[j] = (__bf16)((float)raw[j] * qscale);
          qf[kb] = sc;
        }
#pragma unroll
        for (int r = 0; r < 4; r++) { m_old[r] = -1e30f; l_sum[r] = 0.f; }
#pragma unroll
        for (int nb = 0; nb < 8; nb++) o[nb] = (f32x4){0.f, 0.f, 0.f, 0.f};
      }
      kt = 0;
    } else {
      kt++;
    }
  }
}

// ---------------------------------------------------------------------------
extern "C" void kernel_launch(void* const* d_in, const int* in_sizes, int n_in,
                              void* d_out, int out_size, void* d_ws, size_t ws_size,
                              hipStream_t stream) {
  const float* x      = (const float*)d_in[0];   // (2,2048,2048)
  const float* W_attn = (const float*)d_in[1];   // (2048,6144)
  const float* b_attn = (const float*)d_in[2];   // (6144,)
  const float* W_proj = (const float*)d_in[3];   // (2048,2048)
  const float* b_proj = (const float*)d_in[4];   // (2048,)
  float* out = (float*)d_out;                    // (2,2048,2048) fp32

  char* ws = (char*)d_ws;
  unsigned short* x_bf  = (unsigned short*)(ws);              // 16 MiB
  unsigned short* WaT   = (unsigned short*)(ws + 16777216);   // 24 MiB
  unsigned short* WpT   = (unsigned short*)(ws + 41943040);   // 8 MiB
  unsigned short* qkv   = (unsigned short*)(ws + 50331648);   // 48 MiB
  unsigned short* vT    = (unsigned short*)(ws + 100663296);  // 16 MiB
  unsigned short* y_att = (unsigned short*)(ws + 117440512);  // 16 MiB
  // total 128 MiB

  cvt_f32_bf16_k<<<1024, 256, 0, stream>>>(x, x_bf, 8388608 / 4);
  transpose_f32_bf16<<<dim3(192, 64), dim3(32, 8), 0, stream>>>(W_attn, WaT, 2048, 6144);
  transpose_f32_bf16<<<dim3(64, 64), dim3(32, 8), 0, stream>>>(W_proj, WpT, 2048, 2048);
  gemm_bt<1><<<dim3(48, 32), 256, 0, stream>>>(x_bf, WaT, b_attn, qkv, 4096, 6144, 2048);
  extract_vT_k<<<dim3(64, 4, 32), dim3(32, 8), 0, stream>>>(qkv, vT);
  flash_attn<<<dim3(512), 256, 0, stream>>>(qkv, vT, y_att);
  gemm_bt<0><<<dim3(16, 32), 256, 0, stream>>>(y_att, WpT, b_proj, out, 4096, 2048, 2048);
}

// Round 4
// 423.180 us; speedup vs baseline: 1.4150x; 1.0405x over previous
//
#include <hip/hip_runtime.h>
#include <cstdint>
#include <cstddef>

// ---------------------------------------------------------------------------
// CausalSelfAttention: y = proj(softmax_causal(QK^T/sqrt(HD)) V), QKV = x@W_attn+b
// B=2 T=2048 C=2048 H=16 HD=128. All I/O fp32; internal compute bf16 MFMA.
// ---------------------------------------------------------------------------

typedef __bf16 bf16x8 __attribute__((ext_vector_type(8)));
typedef float  f32x4  __attribute__((ext_vector_type(4)));

__device__ __forceinline__ unsigned short f2bf(float f) {
  unsigned int u = __builtin_bit_cast(unsigned int, f);
  u += 0x7fffu + ((u >> 16) & 1u);       // round-to-nearest-even
  return (unsigned short)(u >> 16);
}

__device__ __forceinline__ void gld16(void* lds, const void* g) {
  // async global->LDS, 16B per lane; LDS dest is wave-uniform base + lane*16
  __builtin_amdgcn_global_load_lds(
      (const __attribute__((address_space(1))) void*)g,
      (__attribute__((address_space(3))) void*)lds, 16, 0, 0);
}

// ---------------------------------------------------------------------------
// fp32 -> bf16 elementwise (x conversion)
// ---------------------------------------------------------------------------
__global__ void cvt_f32_bf16_k(const float* __restrict__ in,
                               unsigned short* __restrict__ out, int n4) {
  int i = blockIdx.x * blockDim.x + threadIdx.x;
  int stride = gridDim.x * blockDim.x;
  for (; i < n4; i += stride) {
    float4 v = ((const float4*)in)[i];
    ushort4 o;
    o.x = f2bf(v.x); o.y = f2bf(v.y); o.z = f2bf(v.z); o.w = f2bf(v.w);
    ((ushort4*)out)[i] = o;
  }
}

// ---------------------------------------------------------------------------
// fp32 (R,C) -> bf16 transposed (C,R)   [for W_attn / W_proj -> B^T layout]
// ---------------------------------------------------------------------------
__global__ void transpose_f32_bf16(const float* __restrict__ in,
                                   unsigned short* __restrict__ out,
                                   int R, int C) {
  __shared__ float tile[32][33];
  int c0 = blockIdx.x * 32, r0 = blockIdx.y * 32;
  int tx = threadIdx.x, ty = threadIdx.y;
#pragma unroll
  for (int i = 0; i < 4; i++)
    tile[ty + i * 8][tx] = in[(size_t)(r0 + ty + i * 8) * C + c0 + tx];
  __syncthreads();
#pragma unroll
  for (int i = 0; i < 4; i++)
    out[(size_t)(c0 + ty + i * 8) * R + r0 + tx] = f2bf(tile[tx][ty + i * 8]);
}

// ---------------------------------------------------------------------------
// extract V^T (B,H,HD,T) bf16 from qkv (B*T, 3C) bf16
// ---------------------------------------------------------------------------
__global__ void extract_vT_k(const unsigned short* __restrict__ qkv,
                             unsigned short* __restrict__ vT) {
  __shared__ unsigned short tile[32][33];
  int bh = blockIdx.z;            // b*16+h
  int b = bh >> 4, h = bh & 15;
  int t0 = blockIdx.x * 32, d0 = blockIdx.y * 32;
  int tx = threadIdx.x, ty = threadIdx.y;
  const unsigned short* src = qkv + (size_t)(b * 2048) * 6144 + 4096 + h * 128;
#pragma unroll
  for (int i = 0; i < 4; i++)
    tile[ty + i * 8][tx] = src[(size_t)(t0 + ty + i * 8) * 6144 + d0 + tx];
  __syncthreads();
  unsigned short* dst = vT + (size_t)bh * 128 * 2048;
#pragma unroll
  for (int i = 0; i < 4; i++)
    dst[(size_t)(d0 + ty + i * 8) * 2048 + t0 + tx] = tile[tx][ty + i * 8];
}

// ---------------------------------------------------------------------------
// m97-style GEMM: C[M,N] = A[M,K](bf16) * BT[N,K](bf16)^T + bias
// 128x128 tile, BK=32, 4 waves (2x2 of 64x64), global_load_lds width-16.
// LDS XOR-swizzled (f(row)=(row>>1)&3) so fragment ds_read_b128 is
// conflict-free: lanes l16=0..7 hit bank-quads {0,4,...,28} distinct,
// l16=8..15 duplicate = 2-way = free (m136). OUT_BF16=1 -> bf16 out.
// ---------------------------------------------------------------------------
template <int OUT_BF16>
__global__ __launch_bounds__(256) void gemm_bt(
    const unsigned short* __restrict__ A, const unsigned short* __restrict__ BT,
    const float* __restrict__ bias, void* __restrict__ Cout,
    int M, int N, int K) {
  __shared__ __align__(16) unsigned short sA[128 * 32];
  __shared__ __align__(16) unsigned short sB[128 * 32];

  const int tid = threadIdx.x, w = tid >> 6, lane = tid & 63;
  const int quad = lane >> 4, l16 = lane & 15;
  const int m0 = blockIdx.y * 128, n0 = blockIdx.x * 128;
  const int wr = w >> 1, wc = w & 1;

  // staging: 512 chunks of 16B per tile; wave w owns chunks [w*128, w*128+128)
  // LDS slot s holds global chunk (row=s>>2, col=(s&3)^((s>>3)&3))
  const int c0 = w * 128 + lane;        // i=0 chunk
  const int c1 = w * 128 + 64 + lane;   // i=1 chunk
  const int sc0 = ((c0 & 3) ^ ((c0 >> 3) & 3));
  const int sc1 = ((c1 & 3) ^ ((c1 >> 3) & 3));
  const unsigned short* gA0 = A + (size_t)(m0 + (c0 >> 2)) * K + sc0 * 8;
  const unsigned short* gA1 = A + (size_t)(m0 + (c1 >> 2)) * K + sc1 * 8;
  const unsigned short* gB0 = BT + (size_t)(n0 + (c0 >> 2)) * K + sc0 * 8;
  const unsigned short* gB1 = BT + (size_t)(n0 + (c1 >> 2)) * K + sc1 * 8;
  unsigned short* lA0 = sA + (size_t)(w * 128) * 8;
  unsigned short* lA1 = sA + (size_t)(w * 128 + 64) * 8;
  unsigned short* lB0 = sB + (size_t)(w * 128) * 8;
  unsigned short* lB1 = sB + (size_t)(w * 128 + 64) * 8;

  // fragment read chunk: slot with s>>2==row and swizzled col == quad
  const int rch = quad ^ ((l16 >> 1) & 3);

  f32x4 acc[4][4] = {};

  for (int k0 = 0; k0 < K; k0 += 32) {
    gld16(lA0, gA0); gld16(lA1, gA1);
    gld16(lB0, gB0); gld16(lB1, gB1);
    gA0 += 32; gA1 += 32; gB0 += 32; gB1 += 32;
    __syncthreads();

    bf16x8 af[4], bfr[4];
#pragma unroll
    for (int mi = 0; mi < 4; mi++)
      af[mi] = *(const bf16x8*)&sA[(wr * 64 + mi * 16 + l16) * 32 + rch * 8];
#pragma unroll
    for (int ni = 0; ni < 4; ni++)
      bfr[ni] = *(const bf16x8*)&sB[(wc * 64 + ni * 16 + l16) * 32 + rch * 8];
#pragma unroll
    for (int mi = 0; mi < 4; mi++)
#pragma unroll
      for (int ni = 0; ni < 4; ni++)
        acc[mi][ni] = __builtin_amdgcn_mfma_f32_16x16x32_bf16(
            af[mi], bfr[ni], acc[mi][ni], 0, 0, 0);
    __syncthreads();
  }

  // epilogue: C/D layout row = quad*4+reg, col = l16
#pragma unroll
  for (int mi = 0; mi < 4; mi++) {
    int row = m0 + wr * 64 + mi * 16 + quad * 4;
#pragma unroll
    for (int ni = 0; ni < 4; ni++) {
      int col = n0 + wc * 64 + ni * 16 + l16;
      float bv = bias[col];
#pragma unroll
      for (int r = 0; r < 4; r++) {
        float v = acc[mi][ni][r] + bv;
        if (OUT_BF16)
          ((unsigned short*)Cout)[(size_t)(row + r) * N + col] = f2bf(v);
        else
          ((float*)Cout)[(size_t)(row + r) * N + col] = v;
      }
    }
  }
}

// ---------------------------------------------------------------------------
// Flash attention (causal). Linear grid of 512:
//   g  = id & 31  -> (b,h) group; all 16 qp-blocks of g land on XCD g%8
//                    (round-robin dispatch heuristic -> K/V stays in one L2)
//   qp = id >> 5  -> complementary q-tile pair (qp, 31-qp): 33 k-iters/block
// Flattened 33-iteration loop over both segments with DOUBLE-BUFFERED K/V
// staging: prefetch tile it+1 right after the top barrier, compute tile it.
// LDS XOR-swizzled (slot (row,chunk) holds global chunk (row, chunk^row&mask))
// so ds_read_b128 is bank-conflict-free under global_load_lds's lane-contiguous
// destination constraint. Q pre-scaled by (1/sqrt(HD))*log2e; exp2f softmax.
// ---------------------------------------------------------------------------
__global__ __launch_bounds__(256) void flash_attn(
    const unsigned short* __restrict__ qkv, const unsigned short* __restrict__ vT,
    unsigned short* __restrict__ yout) {
  __shared__ __align__(16) unsigned short sK[2][64 * 128];    // [t_k][d], swizzle &15
  __shared__ __align__(16) unsigned short sVT[2][128 * 64];   // [d][t_k], swizzle &7
  __shared__ __align__(16) unsigned short sP[4 * 16 * 64];    // per-wave 16x64, swizzle &7

  const int tid = threadIdx.x, w = tid >> 6, lane = tid & 63;
  const int quad = lane >> 4, l16 = lane & 15;
  const int id = blockIdx.x;
  const int g = id & 31;           // (b,h) group -> XCD g%8
  const int qp = id >> 5;          // 0..15
  const int b = g >> 4, h = g & 15;
  const int T = 2048, CC = 6144, HD = 128;
  const float qscale = 0.12753257252f;  // (1/sqrt(128)) * log2(e)

  const unsigned short* gK = qkv + (size_t)(b * T) * CC + 2048 + h * HD;
  const unsigned short* gV = vT + (size_t)(b * 16 + h) * HD * T;
  unsigned short* pw = sP + w * 16 * 64;

  // swizzled staging source pointers (slot -> global chunk), tile-invariant part
  const unsigned short* kSrc[4];
  const unsigned short* vSrc[4];
  unsigned short* kDst[4];
  unsigned short* vDst[4];
#pragma unroll
  for (int i = 0; i < 4; i++) {
    int c = w * 256 + i * 64 + lane;
    int kR = c >> 4, kC = (c & 15) ^ (kR & 15);
    int vR = c >> 3, vC = (c & 7) ^ (vR & 7);
    kSrc[i] = gK + (size_t)kR * CC + kC * 8;
    vSrc[i] = gV + (size_t)vR * T + vC * 8;
    kDst[i] = (unsigned short*)sK + (size_t)(w * 256 + i * 64) * 8;
    vDst[i] = (unsigned short*)sVT + (size_t)(w * 256 + i * 64) * 8;
  }
  const int KBUF = 64 * 128, VBUF = 128 * 64;

  const int qtA = qp, qtB = 31 - qp;
  int qt = qtA, kt = 0;

  // ---- per-segment state ----
  bf16x8 qf[4];
  float m_old[4], l_sum[4];
  f32x4 o[8] = {};
  {
    const size_t qrow = (size_t)(b * T + qt * 64 + w * 16 + l16) * CC + h * HD;
#pragma unroll
    for (int kb = 0; kb < 4; kb++) {
      bf16x8 raw = *(const bf16x8*)&qkv[qrow + kb * 32 + quad * 8];
      bf16x8 sc;
#pragma unroll
      for (int j = 0; j < 8; j++) sc[j] = (__bf16)((float)raw[j] * qscale);
      qf[kb] = sc;
    }
  }
#pragma unroll
  for (int r = 0; r < 4; r++) { m_old[r] = -1e30f; l_sum[r] = 0.f; }

  // stage tile 0 into buffer 0
#pragma unroll
  for (int i = 0; i < 4; i++) {
    gld16(kDst[i], kSrc[i]);
    gld16(vDst[i], vSrc[i]);
  }

  const int total = qtA + qtB + 2;   // = 33
  for (int it = 0; it < total; ++it) {
    __syncthreads();                 // buf[it&1] staged; prev iter's LDS reads done
    const int cur = it & 1;
    const bool segEnd = (kt == qt);

    // prefetch next tile into the other buffer (overlaps with compute below)
    if (it + 1 < total) {
      const int nkt = segEnd ? 0 : kt + 1;
      const int nb_ = (it + 1) & 1;
      const size_t kOff = (size_t)nkt * 64 * CC;   // K rows advance
      const int vOff = nkt * 64;                   // V cols advance
#pragma unroll
      for (int i = 0; i < 4; i++) {
        gld16(kDst[i] + (size_t)nb_ * KBUF * 8 / 8, kSrc[i] + kOff);
        gld16(vDst[i] + (size_t)nb_ * VBUF, vSrc[i] + vOff);
      }
    }

    // S = Q K^T : 16x64 per wave (log2-domain logits; Q pre-scaled)
    const unsigned short* sKc = (const unsigned short*)sK + (size_t)cur * KBUF;
    const unsigned short* sVc = (const unsigned short*)sVT + (size_t)cur * VBUF;
    f32x4 s4[4] = {};
#pragma unroll
    for (int kb = 0; kb < 4; kb++) {
#pragma unroll
      for (int cb = 0; cb < 4; cb++) {
        int rr = cb * 16 + l16;
        int cc = (kb * 4 + quad) ^ l16;
        bf16x8 kf = *(const bf16x8*)&sKc[rr * 128 + cc * 8];
        s4[cb] = __builtin_amdgcn_mfma_f32_16x16x32_bf16(qf[kb], kf, s4[cb], 0, 0, 0);
      }
    }

    // causal mask (diagonal tile only == segment end)
    float sv[4][4];
#pragma unroll
    for (int cb = 0; cb < 4; cb++)
#pragma unroll
      for (int r = 0; r < 4; r++) {
        float v = s4[cb][r];
        if (segEnd) {
          int col = cb * 16 + l16;
          int row = w * 16 + quad * 4 + r;
          if (col > row) v = -1e30f;
        }
        sv[cb][r] = v;
      }

    // online softmax per row (base-2 exponentials)
    float alpha[4];
#pragma unroll
    for (int r = 0; r < 4; r++) {
      float mx = fmaxf(fmaxf(sv[0][r], sv[1][r]), fmaxf(sv[2][r], sv[3][r]));
#pragma unroll
      for (int off = 8; off >= 1; off >>= 1) mx = fmaxf(mx, __shfl_xor(mx, off, 16));
      float m_new = fmaxf(m_old[r], mx);
      float a = exp2f(m_old[r] - m_new);
      float ssum = 0.f;
#pragma unroll
      for (int cb = 0; cb < 4; cb++) {
        float p = exp2f(sv[cb][r] - m_new);
        sv[cb][r] = p;
        ssum += p;
      }
#pragma unroll
      for (int off = 8; off >= 1; off >>= 1) ssum += __shfl_xor(ssum, off, 16);
      l_sum[r] = l_sum[r] * a + ssum;
      m_old[r] = m_new;
      alpha[r] = a;
    }

    // rescale O
#pragma unroll
    for (int nb = 0; nb < 8; nb++)
#pragma unroll
      for (int r = 0; r < 4; r++) o[nb][r] *= alpha[r];

    // P (C/D layout) -> per-wave LDS, swizzled row-major 16x64
#pragma unroll
    for (int cb = 0; cb < 4; cb++) {
#pragma unroll
      for (int r = 0; r < 4; r++) {
        int prow = quad * 4 + r;
        int pcol = cb * 16 + l16;
        int pcc = (pcol >> 3) ^ (prow & 7);
        pw[prow * 64 + pcc * 8 + (pcol & 7)] = f2bf(sv[cb][r]);
      }
    }

    // O += P V
#pragma unroll
    for (int kb2 = 0; kb2 < 2; kb2++) {
      int pcc = (kb2 * 4 + quad) ^ (l16 & 7);
      bf16x8 pf = *(const bf16x8*)&pw[l16 * 64 + pcc * 8];
#pragma unroll
      for (int nb = 0; nb < 8; nb++) {
        int rr = nb * 16 + l16;
        int cc = (kb2 * 4 + quad) ^ (rr & 7);
        bf16x8 vf = *(const bf16x8*)&sVc[rr * 64 + cc * 8];
        o[nb] = __builtin_amdgcn_mfma_f32_16x16x32_bf16(pf, vf, o[nb], 0, 0, 0);
      }
    }

    if (segEnd) {
      // segment epilogue: y[(b*T+t)*C + h*HD + d] bf16
#pragma unroll
      for (int r = 0; r < 4; r++) {
        float inv = 1.0f / l_sum[r];
        size_t orow = (size_t)(b * T + qt * 64 + w * 16 + quad * 4 + r) * 2048 + h * HD;
#pragma unroll
        for (int nb = 0; nb < 8; nb++)
          yout[orow + nb * 16 + l16] = f2bf(o[nb][r] * inv);
      }
      if (it + 1 < total) {
        // reset state for segment B
        qt = qtB;
        const size_t qrow = (size_t)(b * T + qt * 64 + w * 16 + l16) * CC + h * HD;
#pragma unroll
        for (int kb = 0; kb < 4; kb++) {
          bf16x8 raw = *(const bf16x8*)&qkv[qrow + kb * 32 + quad * 8];
          bf16x8 sc;
#pragma unroll
          for (int j = 0; j < 8; j++) sc[j] = (__bf16)((float)raw[j] * qscale);
          qf[kb] = sc;
        }
#pragma unroll
        for (int r = 0; r < 4; r++) { m_old[r] = -1e30f; l_sum[r] = 0.f; }
#pragma unroll
        for (int nb = 0; nb < 8; nb++) o[nb] = (f32x4){0.f, 0.f, 0.f, 0.f};
      }
      kt = 0;
    } else {
      kt++;
    }
  }
}

// ---------------------------------------------------------------------------
extern "C" void kernel_launch(void* const* d_in, const int* in_sizes, int n_in,
                              void* d_out, int out_size, void* d_ws, size_t ws_size,
                              hipStream_t stream) {
  const float* x      = (const float*)d_in[0];   // (2,2048,2048)
  const float* W_attn = (const float*)d_in[1];   // (2048,6144)
  const float* b_attn = (const float*)d_in[2];   // (6144,)
  const float* W_proj = (const float*)d_in[3];   // (2048,2048)
  const float* b_proj = (const float*)d_in[4];   // (2048,)
  float* out = (float*)d_out;                    // (2,2048,2048) fp32

  char* ws = (char*)d_ws;
  unsigned short* x_bf  = (unsigned short*)(ws);              // 16 MiB
  unsigned short* WaT   = (unsigned short*)(ws + 16777216);   // 24 MiB
  unsigned short* WpT   = (unsigned short*)(ws + 41943040);   // 8 MiB
  unsigned short* qkv   = (unsigned short*)(ws + 50331648);   // 48 MiB
  unsigned short* vT    = (unsigned short*)(ws + 100663296);  // 16 MiB
  unsigned short* y_att = (unsigned short*)(ws + 117440512);  // 16 MiB
  // total 128 MiB

  cvt_f32_bf16_k<<<1024, 256, 0, stream>>>(x, x_bf, 8388608 / 4);
  transpose_f32_bf16<<<dim3(192, 64), dim3(32, 8), 0, stream>>>(W_attn, WaT, 2048, 6144);
  transpose_f32_bf16<<<dim3(64, 64), dim3(32, 8), 0, stream>>>(W_proj, WpT, 2048, 2048);
  gemm_bt<1><<<dim3(48, 32), 256, 0, stream>>>(x_bf, WaT, b_attn, qkv, 4096, 6144, 2048);
  extract_vT_k<<<dim3(64, 4, 32), dim3(32, 8), 0, stream>>>(qkv, vT);
  flash_attn<<<dim3(512), 256, 0, stream>>>(qkv, vT, y_att);
  gemm_bt<0><<<dim3(16, 32), 256, 0, stream>>>(y_att, WpT, b_proj, out, 4096, 2048, 2048);
}

// Round 5
// 386.883 us; speedup vs baseline: 1.5478x; 1.0938x over previous
//
#include <hip/hip_runtime.h>
#include <cstdint>
#include <cstddef>

// ---------------------------------------------------------------------------
// CausalSelfAttention: y = proj(softmax_causal(QK^T/sqrt(HD)) V), QKV = x@W_attn+b
// B=2 T=2048 C=2048 H=16 HD=128. All I/O fp32; internal compute bf16 MFMA.
// ---------------------------------------------------------------------------

typedef __bf16 bf16x8 __attribute__((ext_vector_type(8)));
typedef float  f32x4  __attribute__((ext_vector_type(4)));
typedef unsigned short u16x4 __attribute__((ext_vector_type(4)));
typedef unsigned short u16x8 __attribute__((ext_vector_type(8)));

__device__ __forceinline__ unsigned short f2bf(float f) {
  unsigned int u = __builtin_bit_cast(unsigned int, f);
  u += 0x7fffu + ((u >> 16) & 1u);       // round-to-nearest-even
  return (unsigned short)(u >> 16);
}

__device__ __forceinline__ void gld16(void* lds, const void* g) {
  // async global->LDS, 16B per lane; LDS dest is wave-uniform base + lane*16
  __builtin_amdgcn_global_load_lds(
      (const __attribute__((address_space(1))) void*)g,
      (__attribute__((address_space(3))) void*)lds, 16, 0, 0);
}

// ---------------------------------------------------------------------------
// fp32 -> bf16 elementwise (x conversion)
// ---------------------------------------------------------------------------
__global__ void cvt_f32_bf16_k(const float* __restrict__ in,
                               unsigned short* __restrict__ out, int n4) {
  int i = blockIdx.x * blockDim.x + threadIdx.x;
  int stride = gridDim.x * blockDim.x;
  for (; i < n4; i += stride) {
    float4 v = ((const float4*)in)[i];
    ushort4 o;
    o.x = f2bf(v.x); o.y = f2bf(v.y); o.z = f2bf(v.z); o.w = f2bf(v.w);
    ((ushort4*)out)[i] = o;
  }
}

// ---------------------------------------------------------------------------
// fp32 (R,C) -> bf16 transposed (C,R). 64x64 tile, float4 reads, 16B writes.
// LDS tile padded 64x65: both phases land at <=2 lanes/bank (free).
// ---------------------------------------------------------------------------
__global__ __launch_bounds__(256) void transpose_f32_bf16(
    const float* __restrict__ in, unsigned short* __restrict__ out,
    int R, int C) {
  __shared__ float tile[64][65];
  int c0 = blockIdx.x * 64, r0 = blockIdx.y * 64;
  int t = threadIdx.x;
  int lr = t >> 4, lc = (t & 15) * 4;
#pragma unroll
  for (int i = 0; i < 4; i++) {
    int row = lr + i * 16;
    float4 v = *(const float4*)&in[(size_t)(r0 + row) * C + c0 + lc];
    tile[row][lc] = v.x; tile[row][lc + 1] = v.y;
    tile[row][lc + 2] = v.z; tile[row][lc + 3] = v.w;
  }
  __syncthreads();
  int wr = t >> 3, wc = (t & 7) * 8;
#pragma unroll
  for (int i = 0; i < 2; i++) {
    int crow = wr + i * 32;
    u16x8 o;
#pragma unroll
    for (int j = 0; j < 8; j++) o[j] = f2bf(tile[wc + j][crow]);
    *(u16x8*)&out[(size_t)(c0 + crow) * R + r0 + wc] = o;
  }
}

// ---------------------------------------------------------------------------
// extract V^T (B,H,HD,T) bf16 from qkv (B*T, 3C) bf16. 64t x 64d tile.
// 16B global loads/stores; LDS u32-packs t and t+32 per slot (scalar b16
// writes <=2-way; u32 reads <=2-way).
// ---------------------------------------------------------------------------
__global__ __launch_bounds__(256) void extract_vT_k(
    const unsigned short* __restrict__ qkv, unsigned short* __restrict__ vT) {
  __shared__ unsigned int tile32[64][33];   // [d][t&31] packs (t, t+32)
  int bh = blockIdx.z, b = bh >> 4, h = bh & 15;
  int t0 = blockIdx.x * 64, d0 = blockIdx.y * 64;
  int t = threadIdx.x;
  int lr = t >> 3, lc = (t & 7) * 8;
  const unsigned short* src = qkv + (size_t)(b * 2048) * 6144 + 4096 + h * 128;
#pragma unroll
  for (int i = 0; i < 2; i++) {
    int row = lr + i * 32;
    u16x8 v = *(const u16x8*)&src[(size_t)(t0 + row) * 6144 + d0 + lc];
#pragma unroll
    for (int j = 0; j < 8; j++) {
      unsigned short* p = (unsigned short*)&tile32[lc + j][row & 31];
      p[row >> 5] = v[j];
    }
  }
  __syncthreads();
  int dr = t >> 2, tc = (t & 3) * 8;
  u16x8 lo, hi;
#pragma unroll
  for (int j = 0; j < 8; j++) {
    unsigned int u = tile32[dr][tc + j];
    lo[j] = (unsigned short)(u & 0xffffu);
    hi[j] = (unsigned short)(u >> 16);
  }
  unsigned short* dst = vT + (size_t)bh * 128 * 2048 + (size_t)(d0 + dr) * 2048 + t0;
  *(u16x8*)&dst[tc] = lo;
  *(u16x8*)&dst[tc + 32] = hi;
}

// ---------------------------------------------------------------------------
// GEMM: C[M,N] = A[M,K](bf16) * BT[N,K](bf16)^T + bias
// 128x128 tile, BK=64 (32 KB LDS, half the barriers of BK=32), 4 waves,
// global_load_lds width-16. LDS rows are 128B (bank-neutral); chunk XOR
// swizzle c' = c ^ (row&7) gives 8 lanes/bank-quad on ds_read_b128 =
// structural minimum (free). OUT_BF16=1 -> bf16 out.
// ---------------------------------------------------------------------------
template <int OUT_BF16>
__global__ __launch_bounds__(256) void gemm_bt(
    const unsigned short* __restrict__ A, const unsigned short* __restrict__ BT,
    const float* __restrict__ bias, void* __restrict__ Cout,
    int M, int N, int K) {
  __shared__ __align__(16) unsigned short sA[128 * 64];
  __shared__ __align__(16) unsigned short sB[128 * 64];

  const int tid = threadIdx.x, w = tid >> 6, lane = tid & 63;
  const int quad = lane >> 4, l16 = lane & 15;
  const int m0 = blockIdx.y * 128, n0 = blockIdx.x * 128;
  const int wr = w >> 1, wc = w & 1;

  // staging: 1024 16B-chunks per matrix; wave w owns [w*256, w*256+256)
  // LDS slot s holds global chunk (row=s>>3, col=(s&7)^(row&7))
  const unsigned short* gA[4];
  const unsigned short* gB[4];
  unsigned short* lA[4];
  unsigned short* lB[4];
#pragma unroll
  for (int i = 0; i < 4; i++) {
    int c = w * 256 + i * 64 + lane;
    int row = c >> 3, scol = (c & 7) ^ (row & 7);
    gA[i] = A + (size_t)(m0 + row) * K + scol * 8;
    gB[i] = BT + (size_t)(n0 + row) * K + scol * 8;
    lA[i] = sA + (size_t)(w * 256 + i * 64) * 8;
    lB[i] = sB + (size_t)(w * 256 + i * 64) * 8;
  }

  f32x4 acc[4][4] = {};

  for (int k0 = 0; k0 < K; k0 += 64) {
#pragma unroll
    for (int i = 0; i < 4; i++) {
      gld16(lA[i], gA[i]); gld16(lB[i], gB[i]);
      gA[i] += 64; gB[i] += 64;
    }
    __syncthreads();

#pragma unroll
    for (int kk = 0; kk < 2; kk++) {
      const int cc = (kk * 4 + quad) ^ (l16 & 7);
      bf16x8 af[4], bfr[4];
#pragma unroll
      for (int mi = 0; mi < 4; mi++)
        af[mi] = *(const bf16x8*)&sA[(wr * 64 + mi * 16 + l16) * 64 + cc * 8];
#pragma unroll
      for (int ni = 0; ni < 4; ni++)
        bfr[ni] = *(const bf16x8*)&sB[(wc * 64 + ni * 16 + l16) * 64 + cc * 8];
#pragma unroll
      for (int mi = 0; mi < 4; mi++)
#pragma unroll
        for (int ni = 0; ni < 4; ni++)
          acc[mi][ni] = __builtin_amdgcn_mfma_f32_16x16x32_bf16(
              af[mi], bfr[ni], acc[mi][ni], 0, 0, 0);
    }
    __syncthreads();
  }

  // epilogue: C/D layout row = quad*4+reg, col = l16
#pragma unroll
  for (int mi = 0; mi < 4; mi++) {
    int row = m0 + wr * 64 + mi * 16 + quad * 4;
#pragma unroll
    for (int ni = 0; ni < 4; ni++) {
      int col = n0 + wc * 64 + ni * 16 + l16;
      float bv = bias[col];
#pragma unroll
      for (int r = 0; r < 4; r++) {
        float v = acc[mi][ni][r] + bv;
        if (OUT_BF16)
          ((unsigned short*)Cout)[(size_t)(row + r) * N + col] = f2bf(v);
        else
          ((float*)Cout)[(size_t)(row + r) * N + col] = v;
      }
    }
  }
}

// ---------------------------------------------------------------------------
// Flash attention (causal), S^T formulation. Grid 512 linear:
//   g = id&31 -> (b,h) group (XCD-local K/V), qp = id>>5 -> pair (qp, 31-qp).
// Wave w owns q-cols [w*16,w*16+16). S^T = K Q^T via MFMA with A=K-frag,
// B=Q-frag (identical lane layouts). Each lane then holds 16 k-values of ONE
// q-col -> softmax max/sum are in-lane + 2 cross-quad shuffles; m/l/alpha are
// scalars. P^T regs pack r-consecutive k -> 4 ds_write_b64 into per-wave
// P[q][k] (16B-chunk XOR swizzle), read back as A-frag b128 for PV.
// Double-buffered K/V staging via global_load_lds, XOR-swizzled.
// ---------------------------------------------------------------------------
__global__ __launch_bounds__(256) void flash_attn(
    const unsigned short* __restrict__ qkv, const unsigned short* __restrict__ vT,
    unsigned short* __restrict__ yout) {
  __shared__ __align__(16) unsigned short sK[2][64 * 128];    // [t_k][d], swizzle &15
  __shared__ __align__(16) unsigned short sVT[2][128 * 64];   // [d][t_k], swizzle &7
  __shared__ __align__(16) unsigned short sP[4 * 16 * 64];    // per-wave P[q][k], chunk swizzle &7

  const int tid = threadIdx.x, w = tid >> 6, lane = tid & 63;
  const int quad = lane >> 4, l16 = lane & 15;
  const int id = blockIdx.x;
  const int g = id & 31;           // (b,h) group -> XCD g%8
  const int qp = id >> 5;          // 0..15
  const int b = g >> 4, h = g & 15;
  const int T = 2048, CC = 6144, HD = 128;
  const float qscale = 0.12753257252f;  // (1/sqrt(128)) * log2(e)

  const unsigned short* gK = qkv + (size_t)(b * T) * CC + 2048 + h * HD;
  const unsigned short* gV = vT + (size_t)(b * 16 + h) * HD * T;
  unsigned short* pw = sP + w * 16 * 64;

  // swizzled staging source pointers (slot -> global chunk)
  const unsigned short* kSrc[4];
  const unsigned short* vSrc[4];
  unsigned short* kDst[4];
  unsigned short* vDst[4];
#pragma unroll
  for (int i = 0; i < 4; i++) {
    int c = w * 256 + i * 64 + lane;
    int kR = c >> 4, kC = (c & 15) ^ (kR & 15);
    int vR = c >> 3, vC = (c & 7) ^ (vR & 7);
    kSrc[i] = gK + (size_t)kR * CC + kC * 8;
    vSrc[i] = gV + (size_t)vR * T + vC * 8;
    kDst[i] = (unsigned short*)sK + (size_t)(w * 256 + i * 64) * 8;
    vDst[i] = (unsigned short*)sVT + (size_t)(w * 256 + i * 64) * 8;
  }
  const int KBUF = 64 * 128, VBUF = 128 * 64;

  const int qtA = qp, qtB = 31 - qp;
  int qt = qtA, kt = 0;

  // ---- per-segment state (scalar per lane; this lane's q-col = l16) ----
  bf16x8 qf[4];
  float m_old, l_sum;
  f32x4 o[8] = {};
  {
    const size_t qrow = (size_t)(b * T + qt * 64 + w * 16 + l16) * CC + h * HD;
#pragma unroll
    for (int kb = 0; kb < 4; kb++) {
      bf16x8 raw = *(const bf16x8*)&qkv[qrow + kb * 32 + quad * 8];
      bf16x8 sc;
#pragma unroll
      for (int j = 0; j < 8; j++) sc[j] = (__bf16)((float)raw[j] * qscale);
      qf[kb] = sc;
    }
  }
  m_old = -1e30f; l_sum = 0.f;

  // stage tile 0 into buffer 0
#pragma unroll
  for (int i = 0; i < 4; i++) {
    gld16(kDst[i], kSrc[i]);
    gld16(vDst[i], vSrc[i]);
  }

  const int total = qtA + qtB + 2;   // = 33
  for (int it = 0; it < total; ++it) {
    __syncthreads();                 // buf[it&1] staged; prev iter's LDS reads done
    const int cur = it & 1;
    const bool segEnd = (kt == qt);

    // prefetch next tile into the other buffer (overlaps with compute below)
    if (it + 1 < total) {
      const int nkt = segEnd ? 0 : kt + 1;
      const int nb_ = (it + 1) & 1;
      const size_t kOff = (size_t)nkt * 64 * CC;   // K rows advance
      const int vOff = nkt * 64;                   // V cols advance
#pragma unroll
      for (int i = 0; i < 4; i++) {
        gld16(kDst[i] + (size_t)nb_ * KBUF, kSrc[i] + kOff);
        gld16(vDst[i] + (size_t)nb_ * VBUF, vSrc[i] + vOff);
      }
    }

    const unsigned short* sKc = (const unsigned short*)sK + (size_t)cur * KBUF;
    const unsigned short* sVc = (const unsigned short*)sVT + (size_t)cur * VBUF;

    // S^T = K Q^T : 64k x 16q per wave. A = K-frag, B = Q-frag.
    // C/D: k_local = kb*16 + quad*4 + r, q-col = l16.
    f32x4 s4[4] = {};
#pragma unroll
    for (int dc = 0; dc < 4; dc++) {
#pragma unroll
      for (int kb = 0; kb < 4; kb++) {
        int rr = kb * 16 + l16;
        int cc = (dc * 4 + quad) ^ l16;      // rr & 15 == l16
        bf16x8 kf = *(const bf16x8*)&sKc[rr * 128 + cc * 8];
        s4[kb] = __builtin_amdgcn_mfma_f32_16x16x32_bf16(kf, qf[dc], s4[kb], 0, 0, 0);
      }
    }

    // causal mask (diagonal tile only): k_local > q_local
    float sv[4][4];
#pragma unroll
    for (int kb = 0; kb < 4; kb++)
#pragma unroll
      for (int r = 0; r < 4; r++) {
        float v = s4[kb][r];
        if (segEnd) {
          if (kb * 16 + quad * 4 + r > w * 16 + l16) v = -1e30f;
        }
        sv[kb][r] = v;
      }

    // online softmax: in-lane over 16 k-values + 2 cross-quad shuffles
    float mx = sv[0][0];
#pragma unroll
    for (int kb = 0; kb < 4; kb++)
#pragma unroll
      for (int r = 0; r < 4; r++) mx = fmaxf(mx, sv[kb][r]);
    mx = fmaxf(mx, __shfl_xor(mx, 16));
    mx = fmaxf(mx, __shfl_xor(mx, 32));
    float m_new = fmaxf(m_old, mx);
    float a = exp2f(m_old - m_new);
    float ssum = 0.f;
#pragma unroll
    for (int kb = 0; kb < 4; kb++)
#pragma unroll
      for (int r = 0; r < 4; r++) {
        float p = exp2f(sv[kb][r] - m_new);
        sv[kb][r] = p;
        ssum += p;
      }
    ssum += __shfl_xor(ssum, 16);
    ssum += __shfl_xor(ssum, 32);
    l_sum = l_sum * a + ssum;
    m_old = m_new;

    // broadcast alpha across layouts: O rows are q = quad*4+r
    float ar[4];
#pragma unroll
    for (int r = 0; r < 4; r++)
      ar[r] = __shfl(a, (lane & 48) + quad * 4 + r);
#pragma unroll
    for (int nb = 0; nb < 8; nb++)
#pragma unroll
      for (int r = 0; r < 4; r++) o[nb][r] *= ar[r];

    // P store: 4x ds_write_b64 of r-consecutive k into P[q=l16][k],
    // 16B-chunk swizzle c' = c ^ (l16&7)
#pragma unroll
    for (int kb = 0; kb < 4; kb++) {
      u16x4 pk;
#pragma unroll
      for (int r = 0; r < 4; r++) pk[r] = f2bf(sv[kb][r]);
      int c = kb * 2 + (quad >> 1);
      int cp = c ^ (l16 & 7);
      *(u16x4*)&pw[l16 * 64 + cp * 8 + (quad & 1) * 4] = pk;
    }

    // O += P V
#pragma unroll
    for (int kb2 = 0; kb2 < 2; kb2++) {
      int pcc = (kb2 * 4 + quad) ^ (l16 & 7);
      bf16x8 pf = *(const bf16x8*)&pw[l16 * 64 + pcc * 8];
#pragma unroll
      for (int nb = 0; nb < 8; nb++) {
        int rr = nb * 16 + l16;
        int cc = (kb2 * 4 + quad) ^ (rr & 7);
        bf16x8 vf = *(const bf16x8*)&sVc[rr * 64 + cc * 8];
        o[nb] = __builtin_amdgcn_mfma_f32_16x16x32_bf16(pf, vf, o[nb], 0, 0, 0);
      }
    }

    if (segEnd) {
      // epilogue: inv l_sum broadcast like alpha; O rows q = quad*4+r
      float linv = 1.0f / l_sum;
#pragma unroll
      for (int r = 0; r < 4; r++) {
        float ir = __shfl(linv, (lane & 48) + quad * 4 + r);
        size_t orow = (size_t)(b * T + qt * 64 + w * 16 + quad * 4 + r) * 2048 + h * HD;
#pragma unroll
        for (int nb = 0; nb < 8; nb++)
          yout[orow + nb * 16 + l16] = f2bf(o[nb][r] * ir);
      }
      if (it + 1 < total) {
        qt = qtB;
        const size_t qrow = (size_t)(b * T + qt * 64 + w * 16 + l16) * CC + h * HD;
#pragma unroll
        for (int kb = 0; kb < 4; kb++) {
          bf16x8 raw = *(const bf16x8*)&qkv[qrow + kb * 32 + quad * 8];
          bf16x8 sc;
#pragma unroll
          for (int j = 0; j < 8; j++) sc[j] = (__bf16)((float)raw[j] * qscale);
          qf[kb] = sc;
        }
        m_old = -1e30f; l_sum = 0.f;
#pragma unroll
        for (int nb = 0; nb < 8; nb++) o[nb] = (f32x4){0.f, 0.f, 0.f, 0.f};
      }
      kt = 0;
    } else {
      kt++;
    }
  }
}

// ---------------------------------------------------------------------------
extern "C" void kernel_launch(void* const* d_in, const int* in_sizes, int n_in,
                              void* d_out, int out_size, void* d_ws, size_t ws_size,
                              hipStream_t stream) {
  const float* x      = (const float*)d_in[0];   // (2,2048,2048)
  const float* W_attn = (const float*)d_in[1];   // (2048,6144)
  const float* b_attn = (const float*)d_in[2];   // (6144,)
  const float* W_proj = (const float*)d_in[3];   // (2048,2048)
  const float* b_proj = (const float*)d_in[4];   // (2048,)
  float* out = (float*)d_out;                    // (2,2048,2048) fp32

  char* ws = (char*)d_ws;
  unsigned short* x_bf  = (unsigned short*)(ws);              // 16 MiB
  unsigned short* WaT   = (unsigned short*)(ws + 16777216);   // 24 MiB
  unsigned short* WpT   = (unsigned short*)(ws + 41943040);   // 8 MiB
  unsigned short* qkv   = (unsigned short*)(ws + 50331648);   // 48 MiB
  unsigned short* vT    = (unsigned short*)(ws + 100663296);  // 16 MiB
  unsigned short* y_att = (unsigned short*)(ws + 117440512);  // 16 MiB
  // total 128 MiB

  cvt_f32_bf16_k<<<1024, 256, 0, stream>>>(x, x_bf, 8388608 / 4);
  transpose_f32_bf16<<<dim3(96, 32), 256, 0, stream>>>(W_attn, WaT, 2048, 6144);
  transpose_f32_bf16<<<dim3(32, 32), 256, 0, stream>>>(W_proj, WpT, 2048, 2048);
  gemm_bt<1><<<dim3(48, 32), 256, 0, stream>>>(x_bf, WaT, b_attn, qkv, 4096, 6144, 2048);
  extract_vT_k<<<dim3(32, 2, 32), 256, 0, stream>>>(qkv, vT);
  flash_attn<<<dim3(512), 256, 0, stream>>>(qkv, vT, y_att);
  gemm_bt<0><<<dim3(16, 32), 256, 0, stream>>>(y_att, WpT, b_proj, out, 4096, 2048, 2048);
}